// Round 11
// baseline (102.230 us; speedup 1.0000x reference)
//
#include <hip/hip_runtime.h>

// Problem geometry: B=8, H=512, W=512, HID=64, T=16.
#define HH 512
#define WW 512
#define RO 8                      // owned rows per block
#define HALO 15                   // T-1 steps of temporal blocking
#define ROWS (RO + 2 * HALO)      // 38 tile rows
#define OW 8                      // owned words per block (256 cols)
#define TW 10                     // tile words = owned + 1 halo word each side
#define TCOLS (TW * 32)           // 320 tile cols
// Halo-word correctness: dependency cone grows 1 bit/step; clamp garbage in
// the +/-1 halo words never reaches owned bits (verified rounds 2,3,4,6,7,8,10).

// lgkm-only barrier (verified rounds 7/8/10): waits only on LDS ops; global
// float stores stay in flight across steps.
#define STEP_BARRIER() do {                                   \
    asm volatile("s_waitcnt lgkmcnt(0)" ::: "memory");        \
    __builtin_amdgcn_s_barrier();                             \
    __builtin_amdgcn_sched_barrier(0);                        \
} while (0)

// ---------------------------------------------------------------------------
// ONE kernel, ONE dispatch. 1024 blocks (8 images x 64 row-groups x 2 col-
// groups) x 512 threads = 4 blocks/CU. Per block:
//  (a) 512-entry rule (exact fp32, same add order as reference einsum --
//      verified absmax 0.0 rounds 1-10) + pair-LUT (1 KiB, verified R2-R8).
//  (b) self-pack its 38x320 f0 tile into bufA via wave-aligned ballots
//      (R6-fixed split: lane0/lane32 both store at word c>>5); owned cells
//      also copy f0 verbatim to out[0]. No cross-block dependency.
//  (c) 15 steps: compute (R3-verbatim body) -> lgkm-only barrier -> emit one
//      float4/thread (R8 pattern) streaming while the next step computes.
// ---------------------------------------------------------------------------
__global__ __launch_bounds__(512) void mega(const float* __restrict__ f0,
                                            const float* __restrict__ W1,
                                            const float* __restrict__ b1,
                                            const float* __restrict__ W2,
                                            const float* __restrict__ b2,
                                            int hid, float* __restrict__ out,
                                            int n, int T) {
    __shared__ unsigned int rule[512];
    __shared__ unsigned int lutp[256];
    __shared__ unsigned int bufA[ROWS * TW];
    __shared__ unsigned int bufB[ROWS * TW];

    const int tid = threadIdx.x;
    const int cg = blockIdx.x & 1;
    const int rg = (blockIdx.x >> 1) & 63;
    const int b  = blockIdx.x >> 7;
    const int r0 = rg * RO;          // first owned global row
    const int c0 = cg * (OW * 32);   // first owned global column

    // (a) rule table — byte-identical math to the verified build.
    {
        int p = tid;  // 0..511
        float logit = b2[0];
        for (int k = 0; k < hid; ++k) {
            float a = b1[k];
#pragma unroll
            for (int nn = 0; nn < 9; ++nn)
                if (p & (1 << nn)) a += W1[nn * hid + k];
            logit += fmaxf(a, 0.0f) * W2[k];
        }
        rule[p] = (logit > 0.0f) ? 1u : 0u;
    }
    __syncthreads();

    // pair-LUT: idx12 = u4 | m4<<4 | d4<<8 -> 2 bits (cells c, c+1).
    if (tid < 256) {
        unsigned int wv = 0;
#pragma unroll
        for (int k = 0; k < 16; ++k) {
            unsigned int e = (unsigned int)tid * 16u + k;
            unsigned int u = e & 15u, mm = (e >> 4) & 15u, d = (e >> 8) & 15u;
            unsigned int i0 = (u & 7u) | ((mm & 7u) << 3) | ((d & 7u) << 6);
            unsigned int i1 = (u >> 1) | ((mm >> 1) << 3) | ((d >> 1) << 6);
            wv |= (rule[i0] | (rule[i1] << 1)) << (2 * k);
        }
        lutp[tid] = wv;
    }

    // (b) self-pack 38x320 f0 tile + frame-0 verbatim copy of owned cells.
    // i strides 512 (wave-multiple); 320 = 5*64 so no wave straddles a row
    // and each wave's 64 cells start 64-aligned. Last pass: 12160-11776=384
    // active threads = 6 full waves, so every executed __ballot is full-wave.
    // Ballot split (R6-FIXED, verified absmax 0): lane0 stores low word at
    // c>>5; lane32's own c>>5 is ALREADY the next word.
    {
        const float* f0b = f0 + (size_t)b * (HH * WW);
        float* out0 = out + (size_t)b * (HH * WW);
        const int lane = tid & 63;
        for (int i = tid; i < ROWS * TCOLS; i += 512) {
            int l = i / TCOLS, c = i - l * TCOLS;
            int gr = (r0 - HALO + l) & (HH - 1);
            int gc = (c0 - 32 + c) & (WW - 1);
            float v = f0b[(size_t)gr * WW + gc];
            unsigned long long m = __ballot(v > 0.5f);
            if (lane == 0)  bufA[l * TW + (c >> 5)] = (unsigned int)m;
            if (lane == 32) bufA[l * TW + (c >> 5)] = (unsigned int)(m >> 32);
            if (l >= HALO && l < HALO + RO && c >= 32 && c < 32 + 256)
                out0[(size_t)gr * WW + gc] = v;
        }
    }
    __syncthreads();

    unsigned int* oldb = bufA;
    unsigned int* newb = bufB;
    float* outb = out + (size_t)b * (HH * WW);

    // (c) 15 steps; compute body verbatim from R3 (verified absmax 0).
    for (int t = 1; t < T; ++t) {
        const int hi = ROWS - t;          // valid new rows [t, hi)
        const int lq = tid / TW;
        const int w  = tid - lq * TW;
        const int l  = t + lq;
        if (l < hi) {                     // max 36*10 = 360 < 512 threads
            const unsigned int* Ru = oldb + (l - 1) * TW;
            const unsigned int* Rm = oldb + l * TW;
            const unsigned int* Rd = oldb + (l + 1) * TW;
            const int wl = (w == 0) ? 0 : w - 1;        // garbage-safe (cone)
            const int wn = (w == TW - 1) ? TW - 1 : w + 1;
            unsigned long long eu = ((((unsigned long long)Ru[wn] << 32) | Ru[w]) << 1) | (Ru[wl] >> 31);
            unsigned long long em = ((((unsigned long long)Rm[wn] << 32) | Rm[w]) << 1) | (Rm[wl] >> 31);
            unsigned long long ed = ((((unsigned long long)Rd[wn] << 32) | Rd[w]) << 1) | (Rd[wl] >> 31);
            unsigned int ow = 0;
#pragma unroll
            for (int j = 0; j < 16; ++j) {
                unsigned int idx = (unsigned int)((eu >> (2 * j)) & 15ull)
                                 | ((unsigned int)((em >> (2 * j)) & 15ull) << 4)
                                 | ((unsigned int)((ed >> (2 * j)) & 15ull) << 8);
                ow |= ((lutp[idx >> 4] >> ((idx & 15u) * 2)) & 3u) << (2 * j);
            }
            newb[l * TW + w] = ow;
        }
        STEP_BARRIER();    // lgkm-only: newb complete, oldb reads done;
                           // frame stores from previous steps stay in flight.

        // emit step t: owned 8 rows x 256 cols = 512 float4 (one per thread,
        // R8-verified pattern). Overlaps next step's compute (writes oldb
        // only); ds_reads of newb complete by the NEXT barrier.
        float* outt = outb + (size_t)t * n;
        {
            int cell = tid * 4;                        // 0..2044, step 4
            int lr  = cell >> 8;                       // owned row 0..7
            int col = cell & 255;                      // owned col
            unsigned int wv = newb[(HALO + lr) * TW + 1 + (col >> 5)];
            unsigned int nib = (wv >> (col & 31)) & 15u;
            float4 v;
            v.x = (float)(nib & 1u);
            v.y = (float)((nib >> 1) & 1u);
            v.z = (float)((nib >> 2) & 1u);
            v.w = (float)(nib >> 3);
            *(float4*)(outt + (size_t)(r0 + lr) * WW + c0 + col) = v;
        }
        unsigned int* tmp = oldb; oldb = newb; newb = tmp;
    }
}

// ---------------------------------------------------------------------------
// Launch: ONE dispatch, no workspace.
// ---------------------------------------------------------------------------
extern "C" void kernel_launch(void* const* d_in, const int* in_sizes, int n_in,
                              void* d_out, int out_size, void* d_ws, size_t ws_size,
                              hipStream_t stream) {
    const float* f0 = (const float*)d_in[0];
    const float* W1 = (const float*)d_in[1];
    const float* b1 = (const float*)d_in[2];
    const float* W2 = (const float*)d_in[3];
    const float* b2 = (const float*)d_in[4];
    float* out = (float*)d_out;

    const int n = in_sizes[0];        // B*1*H*W = 2,097,152
    const int hid = in_sizes[2];      // 64
    const int T = out_size / n;       // 16
    const int B = n / (HH * WW);      // 8

    mega<<<B * (HH / RO) * 2, 512, 0, stream>>>(f0, W1, b1, W2, b2, hid, out, n, T);
}

// Round 12
// 81.512 us; speedup vs baseline: 1.2542x; 1.2542x over previous
//
#include <hip/hip_runtime.h>

// Problem geometry: B=8, H=512, W=512, HID=64, T=16.
#define HH 512
#define WW 512
#define WPR 16                     // u32 words per global row
#define RO 8                       // owned rows per evolve block
#define HALO 15                    // T-1 steps of temporal blocking
#define ROWS (RO + 2 * HALO)       // 38 tile rows
#define OW 8                       // owned words per block (256 cols)
#define TW 10                      // tile words = owned + 1 halo each side
#define FRAME_WORDS (8 * HH * WPR) // 65536 u32 per bit-frame (B=8)
// Halo-word correctness: dependency cone grows 1 bit/step; clamp garbage in
// the +/-1 halo words never reaches owned bits (verified rounds 2-4,6-8,10,11).

// lgkm-only barrier (verified rounds 7/8/10/11): waits only on LDS ops;
// global stores stay in flight across steps.
#define STEP_BARRIER() do {                                   \
    asm volatile("s_waitcnt lgkmcnt(0)" ::: "memory");        \
    __builtin_amdgcn_s_barrier();                             \
    __builtin_amdgcn_sched_barrier(0);                        \
} while (0)

// ---------------------------------------------------------------------------
// Kernel 1: out[0]=f0 verbatim; bit-pack (f0>0.5) into field. Block 0 builds
// the 512-entry rule + pair-LUT into ws (all math byte-identical to the build
// verified absmax 0.0 in rounds 1-11).
// ---------------------------------------------------------------------------
__global__ __launch_bounds__(512) void init_pack(const float* __restrict__ f0,
                                                 const float* __restrict__ W1,
                                                 const float* __restrict__ b1,
                                                 const float* __restrict__ W2,
                                                 const float* __restrict__ b2,
                                                 int hid,
                                                 float* __restrict__ out,
                                                 unsigned long long* __restrict__ field,
                                                 unsigned int* __restrict__ lutg) {
    __shared__ unsigned int rule[512];
    const int tid = threadIdx.x;
    int c = blockIdx.x * 512 + tid;
    float v = f0[c];
    out[c] = v;
    unsigned long long m = __ballot(v > 0.5f);
    if ((tid & 63) == 0) field[c >> 6] = m;

    if (blockIdx.x == 0) {
        {   // rule table — byte-identical math to the verified build.
            int p = tid;  // 0..511
            float logit = b2[0];
            for (int k = 0; k < hid; ++k) {
                float a = b1[k];
#pragma unroll
                for (int nn = 0; nn < 9; ++nn)
                    if (p & (1 << nn)) a += W1[nn * hid + k];
                logit += fmaxf(a, 0.0f) * W2[k];
            }
            rule[p] = (logit > 0.0f) ? 1u : 0u;
        }
        __syncthreads();
        // pair-LUT: idx12 = u4 | m4<<4 | d4<<8 -> 2 bits (cells c, c+1).
        if (tid < 256) {
            unsigned int wv = 0;
#pragma unroll
            for (int k = 0; k < 16; ++k) {
                unsigned int e = (unsigned int)tid * 16u + k;
                unsigned int u = e & 15u, mm = (e >> 4) & 15u, d = (e >> 8) & 15u;
                unsigned int i0 = (u & 7u) | ((mm & 7u) << 3) | ((d & 7u) << 6);
                unsigned int i1 = (u >> 1) | ((mm >> 1) << 3) | ((d >> 1) << 6);
                wv |= (rule[i0] | (rule[i1] << 1)) << (2 * k);
            }
            lutg[tid] = wv;
        }
    }
}

// ---------------------------------------------------------------------------
// Kernel 2 "evolve": bit-domain only. 1024 blocks (8 images x 64 row-groups
// x 2 col-groups) x 512 thr = 4 blocks/CU = 32 waves/CU. Preamble: 1 KiB LUT
// + 38x10-word tile. 15 steps (R3-verbatim body, verified absmax 0); owning
// threads store their freshly computed word straight from register to the
// global bit-frame (512 B/block/step) BEFORE the lgkm-only barrier — stores
// stream across the whole loop. No float traffic anywhere.
// ---------------------------------------------------------------------------
__global__ __launch_bounds__(512) void evolve(const unsigned int* __restrict__ field,
                                              const unsigned int* __restrict__ lutg,
                                              unsigned int* __restrict__ fields,
                                              int T) {
    __shared__ unsigned int lutp[256];
    __shared__ unsigned int bufA[ROWS * TW];
    __shared__ unsigned int bufB[ROWS * TW];

    const int tid = threadIdx.x;
    const int cg = blockIdx.x & 1;
    const int rg = (blockIdx.x >> 1) & 63;
    const int b  = blockIdx.x >> 7;
    const int r0 = rg * RO;          // first owned global row
    const int q0 = cg * OW;          // first owned global word

    if (tid < 256) lutp[tid] = lutg[tid];
    {
        const unsigned int* F = field + b * (HH * WPR);
        for (int i = tid; i < ROWS * TW; i += 512) {
            int l = i / TW, tw = i - l * TW;
            int g  = (r0 - HALO + l) & (HH - 1);
            int gw = (q0 - 1 + tw) & (WPR - 1);
            bufA[i] = F[g * WPR + gw];
        }
    }
    __syncthreads();

    unsigned int* oldb = bufA;
    unsigned int* newb = bufB;

    for (int t = 1; t < T; ++t) {
        const int hi = ROWS - t;          // valid new rows [t, hi)
        const int lq = tid / TW;
        const int w  = tid - lq * TW;
        const int l  = t + lq;
        if (l < hi) {                     // max 36*10 = 360 < 512 threads
            const unsigned int* Ru = oldb + (l - 1) * TW;
            const unsigned int* Rm = oldb + l * TW;
            const unsigned int* Rd = oldb + (l + 1) * TW;
            const int wl = (w == 0) ? 0 : w - 1;        // garbage-safe (cone)
            const int wn = (w == TW - 1) ? TW - 1 : w + 1;
            unsigned long long eu = ((((unsigned long long)Ru[wn] << 32) | Ru[w]) << 1) | (Ru[wl] >> 31);
            unsigned long long em = ((((unsigned long long)Rm[wn] << 32) | Rm[w]) << 1) | (Rm[wl] >> 31);
            unsigned long long ed = ((((unsigned long long)Rd[wn] << 32) | Rd[w]) << 1) | (Rd[wl] >> 31);
            unsigned int ow = 0;
#pragma unroll
            for (int j = 0; j < 16; ++j) {
                unsigned int idx = (unsigned int)((eu >> (2 * j)) & 15ull)
                                 | ((unsigned int)((em >> (2 * j)) & 15ull) << 4)
                                 | ((unsigned int)((ed >> (2 * j)) & 15ull) << 8);
                ow |= ((lutp[idx >> 4] >> ((idx & 15u) * 2)) & 3u) << (2 * j);
            }
            newb[l * TW + w] = ow;
            // owned word -> global bit-frame, straight from register,
            // pre-barrier (lgkm barrier does not wait on it).
            if (l >= HALO && l < HALO + RO && w >= 1 && w <= OW)
                fields[(size_t)(t - 1) * FRAME_WORDS + b * (HH * WPR)
                       + (size_t)(r0 + l - HALO) * WPR + (q0 + w - 1)] = ow;
        }
        STEP_BARRIER();    // lgkm-only: newb complete, oldb reads done.
        unsigned int* tmp = oldb; oldb = newb; newb = tmp;
    }
}

// ---------------------------------------------------------------------------
// Kernel 3 "expand" (R9-verbatim, verified absmax 0): pure streaming, no LDS,
// no barriers. 15360 blocks x 512 thr; one float4 per thread; word fetch
// broadcast across 8 consecutive lanes; 1 KiB contiguous stores per wave.
// ---------------------------------------------------------------------------
__global__ __launch_bounds__(512) void expand(const unsigned int* __restrict__ fields,
                                              float* __restrict__ out, int n) {
    const int f  = blockIdx.x >> 10;                         // frame-1 (0..14)
    const int g4 = ((blockIdx.x & 1023) << 9) + threadIdx.x; // f4 idx in frame
    unsigned int wv = fields[(size_t)f * FRAME_WORDS + (g4 >> 3)];
    unsigned int nib = (wv >> ((g4 & 7) * 4)) & 15u;
    float4 v;
    v.x = (float)(nib & 1u);
    v.y = (float)((nib >> 1) & 1u);
    v.z = (float)((nib >> 2) & 1u);
    v.w = (float)(nib >> 3);
    ((float4*)out)[(size_t)(f + 1) * (n >> 2) + g4] = v;
}

// ---------------------------------------------------------------------------
// Launch: init_pack -> evolve -> expand (3 dispatches).
// d_ws: [0, 1024)                pair-LUT (256 u32)
//       [1024, 1024+256K)        packed step-0 bit field
//       [1024+256K, +15*256K)    bit-frames for steps 1..15 (3.93 MB)
// ---------------------------------------------------------------------------
extern "C" void kernel_launch(void* const* d_in, const int* in_sizes, int n_in,
                              void* d_out, int out_size, void* d_ws, size_t ws_size,
                              hipStream_t stream) {
    const float* f0 = (const float*)d_in[0];
    const float* W1 = (const float*)d_in[1];
    const float* b1 = (const float*)d_in[2];
    const float* W2 = (const float*)d_in[3];
    const float* b2 = (const float*)d_in[4];
    float* out = (float*)d_out;

    const int n = in_sizes[0];        // B*1*H*W = 2,097,152
    const int hid = in_sizes[2];      // 64
    const int T = out_size / n;       // 16
    const int B = n / (HH * WW);      // 8

    char* ws = (char*)d_ws;
    unsigned int* lutg = (unsigned int*)ws;
    unsigned long long* fld = (unsigned long long*)(ws + 1024);
    unsigned int* frames = (unsigned int*)(ws + 1024 + (size_t)(n / 8));

    init_pack<<<n / 512, 512, 0, stream>>>(f0, W1, b1, W2, b2, hid, out, fld, lutg);
    evolve<<<B * (HH / RO) * 2, 512, 0, stream>>>((const unsigned int*)fld, lutg,
                                                  frames, T);
    expand<<<15 * 1024, 512, 0, stream>>>(frames, out, n);
}